// Round 1
// baseline (114.170 us; speedup 1.0000x reference)
//
#include <hip/hip_runtime.h>
#include <hip/hip_bf16.h>

typedef short bf16x8 __attribute__((ext_vector_type(8)));
typedef float f32x4 __attribute__((ext_vector_type(4)));

#define GLOAD(gp, lp)                                                          \
    __builtin_amdgcn_global_load_lds(                                          \
        (const __attribute__((address_space(1))) void*)(gp),                   \
        (__attribute__((address_space(3))) void*)(lp), 16, 0, 0)

// Problem sizes: B=16, C=256, HW=4096 (64*64)
static constexpr int kB = 16;
static constexpr int kC = 256;
static constexpr int kHW = 4096;

// Workspace layout (float offsets)
static constexpr int OFF_INVC_T = 0;        // 65536 floats: 1/||teacher[:,hw]||
static constexpr int OFF_INVC_S = 65536;    // 65536 floats
static constexpr int OFF_INVD_T = 131072;   // 4096 floats: 1/||u_t[b,c,:]||
static constexpr int OFF_INVD_S = 135168;   // 4096 floats
static constexpr int OFF_EXPS   = 139264;   // 16 floats: sum exp(sim/T) per b
static constexpr int OFF_POSS   = 139280;   // 16 floats: sum diag(sim) per b
static constexpr size_t OFF_U_BYTES = 139296ull * 4ull;   // bf16 u_t then u_s
static constexpr size_t U_ELEMS = (size_t)kB * kC * kHW;  // 16777216

// ---------------- Kernel 1: channel norms (reduce over C, stride HW) --------
__global__ void colnorm_k(const float* __restrict__ ten,
                          const float* __restrict__ stu,
                          float* __restrict__ ws)
{
    int tid = threadIdx.x;
    if (blockIdx.x == 0 && blockIdx.y == 0 && tid < 32)
        ws[OFF_EXPS + tid] = 0.0f;   // zero exp/pos accumulators for this call

    const float* src = (blockIdx.y == 0) ? ten : stu;
    float* invC = ws + ((blockIdx.y == 0) ? OFF_INVC_T : OFF_INVC_S);

    int g  = blockIdx.x * 256 + tid;     // 0 .. 65535 = b*HW + hw
    int b  = g >> 12;
    int hw = g & 4095;
    const float* p = src + (size_t)b * (kC * kHW) + hw;

    float acc = 0.0f;
#pragma unroll 8
    for (int c = 0; c < kC; ++c) {
        float v = p[(size_t)c * kHW];
        acc += v * v;
    }
    invC[g] = 1.0f / fmaxf(sqrtf(acc), 1e-12f);
}

// ---------------- Kernel 2: u = x*invC -> bf16, row norms over HW -----------
__device__ __forceinline__ unsigned short f2bf(float f) {
    __hip_bfloat16 h = __float2bfloat16(f);
    return __builtin_bit_cast(unsigned short, h);
}

__global__ void rownorm_k(const float* __restrict__ ten,
                          const float* __restrict__ stu,
                          float* __restrict__ ws)
{
    int tid = threadIdx.x;
    int bc  = blockIdx.x;               // b*256 + c
    int b   = bc >> 8;
    bool isT = (blockIdx.y == 0);
    const float* src  = isT ? ten : stu;
    const float* invC = ws + (isT ? OFF_INVC_T : OFF_INVC_S);
    float* invD       = ws + (isT ? OFF_INVD_T : OFF_INVD_S);
    unsigned short* u = (unsigned short*)((char*)ws + OFF_U_BYTES) + (isT ? 0 : U_ELEMS);

    size_t rowBase = (size_t)bc * kHW;
    const float* crow = invC + b * kHW;

    float ss = 0.0f;
#pragma unroll
    for (int it = 0; it < 4; ++it) {
        int off = it * 1024 + tid * 4;
        float4 v = *(const float4*)(src + rowBase + off);
        float4 s = *(const float4*)(crow + off);
        float u0 = v.x * s.x, u1 = v.y * s.y, u2 = v.z * s.z, u3 = v.w * s.w;
        ss += u0 * u0 + u1 * u1 + u2 * u2 + u3 * u3;
        ushort4 o;
        o.x = f2bf(u0); o.y = f2bf(u1); o.z = f2bf(u2); o.w = f2bf(u3);
        *(ushort4*)(u + rowBase + off) = o;
    }
#pragma unroll
    for (int o = 32; o; o >>= 1) ss += __shfl_down(ss, o);
    __shared__ float red[4];
    if ((tid & 63) == 0) red[tid >> 6] = ss;
    __syncthreads();
    if (tid == 0)
        invD[bc] = 1.0f / fmaxf(sqrtf(red[0] + red[1] + red[2] + red[3]), 1e-12f);
}

// ---------------- Kernel 3: batched GEMM (u_s @ u_t^T) + fused exp/diag -----
// grid: x = 16 tiles (4x4 of 64x64 over 256x256), y = batch. 256 thr = 4 waves.
__global__ __launch_bounds__(256) void gemm_fused_k(float* __restrict__ ws)
{
    const unsigned short* uT = (const unsigned short*)((const char*)ws + OFF_U_BYTES);
    const unsigned short* uS = uT + U_ELEMS;
    const float* invDt = ws + OFF_INVD_T;
    const float* invDs = ws + OFF_INVD_S;

    __shared__ __align__(16) unsigned short As[2][4096];  // student tile 64x64
    __shared__ __align__(16) unsigned short Bs[2][4096];  // teacher tile 64x64
    __shared__ float redE[4], redP[4];

    int tid  = threadIdx.x;
    int b    = blockIdx.y;
    int tr   = blockIdx.x >> 2, tc = blockIdx.x & 3;
    int lane = tid & 63, wid = tid >> 6;
    int wr   = wid >> 1, wc = wid & 1;

    // Staging: thread t fills LDS bytes [D, D+16). Pre-swizzle the GLOBAL
    // source so that a swizzled read (byte ^= (row&7)<<4) sees linear data
    // (rule 21: both-sides-or-neither).
    int D0  = tid * 16;
    int r0s = D0 >> 7;
    int c0s = ((D0 & 127) ^ ((r0s & 7) << 4)) >> 1;   // bf16 col within row
    int D1  = 4096 + tid * 16;
    int r1s = D1 >> 7;
    int c1s = ((D1 & 127) ^ ((r1s & 7) << 4)) >> 1;

    const unsigned short* gA = uS + ((size_t)(b * kC + tr * 64) << 12);
    const unsigned short* gB = uT + ((size_t)(b * kC + tc * 64) << 12);

    f32x4 acc[2][2] = {};

    // prologue stage of k-chunk 0
    GLOAD(gA + ((size_t)r0s << 12) + c0s, (char*)As[0] + D0);
    GLOAD(gA + ((size_t)r1s << 12) + c1s, (char*)As[0] + D1);
    GLOAD(gB + ((size_t)r0s << 12) + c0s, (char*)Bs[0] + D0);
    GLOAD(gB + ((size_t)r1s << 12) + c1s, (char*)Bs[0] + D1);
    __syncthreads();

    int cur = 0;
    for (int it = 0; it < 64; ++it) {
        if (it + 1 < 64) {
            int k0 = (it + 1) * 64;
            GLOAD(gA + ((size_t)r0s << 12) + k0 + c0s, (char*)As[cur ^ 1] + D0);
            GLOAD(gA + ((size_t)r1s << 12) + k0 + c1s, (char*)As[cur ^ 1] + D1);
            GLOAD(gB + ((size_t)r0s << 12) + k0 + c0s, (char*)Bs[cur ^ 1] + D0);
            GLOAD(gB + ((size_t)r1s << 12) + k0 + c1s, (char*)Bs[cur ^ 1] + D1);
        }
        const char* Ab = (const char*)As[cur];
        const char* Bb = (const char*)Bs[cur];
#pragma unroll
        for (int ks = 0; ks < 2; ++ks) {
            bf16x8 av[2], bv[2];
            int kb = ks * 64 + (lane >> 4) * 16;   // byte col of this lane's 8 bf16
#pragma unroll
            for (int f = 0; f < 2; ++f) {
                int row = wr * 32 + f * 16 + (lane & 15);
                av[f] = *(const bf16x8*)(Ab + (row << 7) + (kb ^ ((row & 7) << 4)));
                int col = wc * 32 + f * 16 + (lane & 15);
                bv[f] = *(const bf16x8*)(Bb + (col << 7) + (kb ^ ((col & 7) << 4)));
            }
#pragma unroll
            for (int fr = 0; fr < 2; ++fr)
#pragma unroll
                for (int fc = 0; fc < 2; ++fc)
                    acc[fr][fc] = __builtin_amdgcn_mfma_f32_16x16x32_bf16(
                        av[fr], bv[fc], acc[fr][fc], 0, 0, 0);
        }
        __syncthreads();   // drains vmcnt(0): next buffer staged, reads done
        cur ^= 1;
    }

    // Epilogue: scale by row/col inv norms, accumulate exp(sim/T) and diag.
    float eAcc = 0.0f, pAcc = 0.0f;
    int gr0 = tr * 64 + wr * 32;
    int gc0 = tc * 64 + wc * 32;
#pragma unroll
    for (int fr = 0; fr < 2; ++fr)
#pragma unroll
        for (int fc = 0; fc < 2; ++fc) {
            int col = gc0 + fc * 16 + (lane & 15);
            float st = invDt[b * kC + col];
#pragma unroll
            for (int j = 0; j < 4; ++j) {
                int row = gr0 + fr * 16 + (lane >> 4) * 4 + j;   // C/D layout (m89)
                float v = acc[fr][fc][j] * invDs[b * kC + row] * st;
                eAcc += __expf(2.0f * v);                        // 1/T = 2
                pAcc += (row == col) ? v : 0.0f;
            }
        }
#pragma unroll
    for (int o = 32; o; o >>= 1) {
        eAcc += __shfl_down(eAcc, o);
        pAcc += __shfl_down(pAcc, o);
    }
    if (lane == 0) { redE[wid] = eAcc; redP[wid] = pAcc; }
    __syncthreads();
    if (tid == 0) {
        atomicAdd(ws + OFF_EXPS + b, redE[0] + redE[1] + redE[2] + redE[3]);
        atomicAdd(ws + OFF_POSS + b, redP[0] + redP[1] + redP[2] + redP[3]);
    }
}

// ---------------- Kernel 4: finalize scalar loss -----------------------------
__global__ void finalize_k(const float* __restrict__ ws, float* __restrict__ out)
{
    if (threadIdx.x == 0) {
        const float* expSum = ws + OFF_EXPS;
        const float* posSum = ws + OFF_POSS;
        float loss = 0.0f;
        for (int b = 0; b < kB; ++b)
            loss += -2.0f * posSum[b] / (float)kC + logf(expSum[b]);
        out[0] = loss / (float)kB;
    }
}

extern "C" void kernel_launch(void* const* d_in, const int* in_sizes, int n_in,
                              void* d_out, int out_size, void* d_ws, size_t ws_size,
                              hipStream_t stream)
{
    const float* ten = (const float*)d_in[0];   // teacher_vectors
    const float* stu = (const float*)d_in[1];   // student_vectors
    float* ws  = (float*)d_ws;
    float* out = (float*)d_out;

    colnorm_k<<<dim3(256, 2), 256, 0, stream>>>(ten, stu, ws);
    rownorm_k<<<dim3(4096, 2), 256, 0, stream>>>(ten, stu, ws);
    gemm_fused_k<<<dim3(16, 16), 256, 0, stream>>>(ws);
    finalize_k<<<1, 64, 0, stream>>>(ws, out);
}

// Round 2
// 110.445 us; speedup vs baseline: 1.0337x; 1.0337x over previous
//
#include <hip/hip_runtime.h>
#include <hip/hip_bf16.h>

typedef short bf16x8 __attribute__((ext_vector_type(8)));
typedef float f32x4 __attribute__((ext_vector_type(4)));

#define GLOAD(gp, lp)                                                          \
    __builtin_amdgcn_global_load_lds(                                          \
        (const __attribute__((address_space(1))) void*)(gp),                   \
        (__attribute__((address_space(3))) void*)(lp), 16, 0, 0)

// Problem sizes: B=16, C=256, HW=4096 (64*64)
static constexpr int kB = 16;
static constexpr int kC = 256;
static constexpr int kHW = 4096;

// Workspace layout (float offsets)
static constexpr int OFF_INVC_T = 0;        // 65536 floats
static constexpr int OFF_INVC_S = 65536;    // 65536 floats
static constexpr int OFF_INVD_T = 131072;   // 4096 floats
static constexpr int OFF_INVD_S = 135168;   // 4096 floats
static constexpr int OFF_EXPS   = 139264;   // 16 floats
static constexpr int OFF_POSS   = 139280;   // 16 floats
static constexpr size_t OFF_U_BYTES = 139296ull * 4ull;       // bf16 u_t then u_s
static constexpr size_t U_ELEMS = (size_t)kB * kC * kHW;      // 16777216 per tensor
// psim after u: u occupies 2*U_ELEMS*2 bytes = 16777216 floats-worth
static constexpr size_t OFF_PSIM = 139296ull + 16777216ull;   // float offset
// psim size = KS * 16 * 65536 floats

// ---------------- Kernel 1: channel norms (reduce over C, stride HW) --------
__global__ void colnorm_k(const float* __restrict__ ten,
                          const float* __restrict__ stu,
                          float* __restrict__ ws)
{
    int tid = threadIdx.x;
    if (blockIdx.x == 0 && blockIdx.y == 0 && tid < 32)
        ws[OFF_EXPS + tid] = 0.0f;   // zero exp/pos accumulators for this call

    const float* src = (blockIdx.y == 0) ? ten : stu;
    float* invC = ws + ((blockIdx.y == 0) ? OFF_INVC_T : OFF_INVC_S);

    int g  = blockIdx.x * 256 + tid;     // 0 .. 65535 = b*HW + hw
    int b  = g >> 12;
    int hw = g & 4095;
    const float* p = src + (size_t)b * (kC * kHW) + hw;

    float a0 = 0.0f, a1 = 0.0f;
#pragma unroll 8
    for (int c = 0; c < kC; c += 2) {
        float v0 = p[(size_t)c * kHW];
        float v1 = p[(size_t)(c + 1) * kHW];
        a0 += v0 * v0;
        a1 += v1 * v1;
    }
    invC[g] = 1.0f / fmaxf(sqrtf(a0 + a1), 1e-12f);
}

// ---------------- Kernel 2: u = x*invC -> bf16, row norms over HW -----------
__device__ __forceinline__ unsigned short f2bf(float f) {
    __hip_bfloat16 h = __float2bfloat16(f);
    return __builtin_bit_cast(unsigned short, h);
}

__global__ void rownorm_k(const float* __restrict__ ten,
                          const float* __restrict__ stu,
                          float* __restrict__ ws)
{
    int tid = threadIdx.x;
    int bc  = blockIdx.x;               // b*256 + c
    int b   = bc >> 8;
    bool isT = (blockIdx.y == 0);
    const float* src  = isT ? ten : stu;
    const float* invC = ws + (isT ? OFF_INVC_T : OFF_INVC_S);
    float* invD       = ws + (isT ? OFF_INVD_T : OFF_INVD_S);
    unsigned short* u = (unsigned short*)((char*)ws + OFF_U_BYTES) + (isT ? 0 : U_ELEMS);

    size_t rowBase = (size_t)bc * kHW;
    const float* crow = invC + b * kHW;

    float ss = 0.0f;
#pragma unroll
    for (int it = 0; it < 4; ++it) {
        int off = it * 1024 + tid * 4;
        float4 v = *(const float4*)(src + rowBase + off);
        float4 s = *(const float4*)(crow + off);
        float u0 = v.x * s.x, u1 = v.y * s.y, u2 = v.z * s.z, u3 = v.w * s.w;
        ss += u0 * u0 + u1 * u1 + u2 * u2 + u3 * u3;
        ushort4 o;
        o.x = f2bf(u0); o.y = f2bf(u1); o.z = f2bf(u2); o.w = f2bf(u3);
        *(ushort4*)(u + rowBase + off) = o;
    }
#pragma unroll
    for (int o = 32; o; o >>= 1) ss += __shfl_down(ss, o);
    __shared__ float red[4];
    if ((tid & 63) == 0) red[tid >> 6] = ss;
    __syncthreads();
    if (tid == 0)
        invD[bc] = 1.0f / fmaxf(sqrtf(red[0] + red[1] + red[2] + red[3]), 1e-12f);
}

// ---------------- Kernel 3: batched GEMM partials (K-split) ------------------
// grid.x = 256*KS blocks (XCD-chunk-swizzled). Each block: 64x64 tile over
// K = 4096/KS, writes raw partial dot-product tile to psim[kz*16+b].
__global__ __launch_bounds__(256) void gemm_part_k(float* __restrict__ ws,
                                                   int kIters)
{
    const unsigned short* uT = (const unsigned short*)((const char*)ws + OFF_U_BYTES);
    const unsigned short* uS = uT + U_ELEMS;
    float* psim = ws + OFF_PSIM;

    __shared__ __align__(16) unsigned short As[2][4096];  // student tile 64x64
    __shared__ __align__(16) unsigned short Bs[2][4096];  // teacher tile 64x64

    int tid = threadIdx.x;
    // XCD-chunked bijective swizzle: consecutive work-ids (sharing A/B slabs)
    // stay on one XCD. nwg = 256*KS is a multiple of 8.
    int bid = blockIdx.x;
    int cpx = gridDim.x >> 3;
    int w   = (bid & 7) * cpx + (bid >> 3);
    int tile = w & 15;                   // 4x4 tiles of one (kz,b)
    int g    = w >> 4;
    int b    = g & 15;
    int kz   = g >> 4;
    int tr   = tile >> 2, tc = tile & 3;
    int lane = tid & 63, wid = tid >> 6;
    int wr   = wid >> 1, wc = wid & 1;

    int k0base = kz * (kIters * 64);

    // Staging addressing: pre-swizzled global source, linear LDS dest,
    // swizzled read (byte ^= (row&7)<<4). Rule 21: both-sides-or-neither.
    int D0  = tid * 16;
    int r0s = D0 >> 7;
    int c0s = ((D0 & 127) ^ ((r0s & 7) << 4)) >> 1;
    int D1  = 4096 + tid * 16;
    int r1s = D1 >> 7;
    int c1s = ((D1 & 127) ^ ((r1s & 7) << 4)) >> 1;

    const unsigned short* gA = uS + ((size_t)(b * kC + tr * 64) << 12) + k0base;
    const unsigned short* gB = uT + ((size_t)(b * kC + tc * 64) << 12) + k0base;

    f32x4 acc[2][2] = {};

    GLOAD(gA + ((size_t)r0s << 12) + c0s, (char*)As[0] + D0);
    GLOAD(gA + ((size_t)r1s << 12) + c1s, (char*)As[0] + D1);
    GLOAD(gB + ((size_t)r0s << 12) + c0s, (char*)Bs[0] + D0);
    GLOAD(gB + ((size_t)r1s << 12) + c1s, (char*)Bs[0] + D1);
    __syncthreads();

    int cur = 0;
    for (int it = 0; it < kIters; ++it) {
        if (it + 1 < kIters) {
            int k0 = (it + 1) * 64;
            GLOAD(gA + ((size_t)r0s << 12) + k0 + c0s, (char*)As[cur ^ 1] + D0);
            GLOAD(gA + ((size_t)r1s << 12) + k0 + c1s, (char*)As[cur ^ 1] + D1);
            GLOAD(gB + ((size_t)r0s << 12) + k0 + c0s, (char*)Bs[cur ^ 1] + D0);
            GLOAD(gB + ((size_t)r1s << 12) + k0 + c1s, (char*)Bs[cur ^ 1] + D1);
        }
        const char* Ab = (const char*)As[cur];
        const char* Bb = (const char*)Bs[cur];
#pragma unroll
        for (int ks = 0; ks < 2; ++ks) {
            bf16x8 av[2], bv[2];
            int kb = ks * 64 + (lane >> 4) * 16;
#pragma unroll
            for (int f = 0; f < 2; ++f) {
                int row = wr * 32 + f * 16 + (lane & 15);
                av[f] = *(const bf16x8*)(Ab + (row << 7) + (kb ^ ((row & 7) << 4)));
                int col = wc * 32 + f * 16 + (lane & 15);
                bv[f] = *(const bf16x8*)(Bb + (col << 7) + (kb ^ ((col & 7) << 4)));
            }
#pragma unroll
            for (int fr = 0; fr < 2; ++fr)
#pragma unroll
                for (int fc = 0; fc < 2; ++fc)
                    acc[fr][fc] = __builtin_amdgcn_mfma_f32_16x16x32_bf16(
                        av[fr], bv[fc], acc[fr][fc], 0, 0, 0);
        }
        __syncthreads();
        cur ^= 1;
    }

    // Write raw partial tile (scaling + exp deferred to reduce_k).
    float* pt = psim + ((size_t)(kz * 16 + b) << 16);
#pragma unroll
    for (int fr = 0; fr < 2; ++fr)
#pragma unroll
        for (int fc = 0; fc < 2; ++fc) {
            int col = tc * 64 + wc * 32 + fc * 16 + (lane & 15);
#pragma unroll
            for (int j = 0; j < 4; ++j) {
                int row = tr * 64 + wr * 32 + fr * 16 + (lane >> 4) * 4 + j;
                pt[row * 256 + col] = acc[fr][fc][j];
            }
        }
}

// ---------------- Kernel 4: sum partials + scale + fused exp/diag reduce ----
__global__ __launch_bounds__(256) void reduce_k(float* __restrict__ ws, int KS)
{
    const float* psim  = ws + OFF_PSIM;
    const float* invDt = ws + OFF_INVD_T;
    const float* invDs = ws + OFF_INVD_S;

    int b     = blockIdx.x >> 6;
    int local = ((blockIdx.x & 63) << 10) + threadIdx.x * 4;   // 0..65535
    int row   = local >> 8;
    int col   = local & 255;

    float4 s = {0.0f, 0.0f, 0.0f, 0.0f};
    for (int ks = 0; ks < KS; ++ks) {
        float4 v = *(const float4*)(psim + (((size_t)(ks * 16 + b)) << 16) + local);
        s.x += v.x; s.y += v.y; s.z += v.z; s.w += v.w;
    }
    float  ds = invDs[b * 256 + row];
    float4 dt = *(const float4*)(invDt + b * 256 + col);
    float v0 = s.x * ds * dt.x;
    float v1 = s.y * ds * dt.y;
    float v2 = s.z * ds * dt.z;
    float v3 = s.w * ds * dt.w;

    float eAcc = __expf(2.0f * v0) + __expf(2.0f * v1) +
                 __expf(2.0f * v2) + __expf(2.0f * v3);
    float pAcc = 0.0f;
    if (row == col)     pAcc = v0;
    if (row == col + 1) pAcc = v1;
    if (row == col + 2) pAcc = v2;
    if (row == col + 3) pAcc = v3;

#pragma unroll
    for (int o = 32; o; o >>= 1) {
        eAcc += __shfl_down(eAcc, o);
        pAcc += __shfl_down(pAcc, o);
    }
    __shared__ float redE[4], redP[4];
    int lane = threadIdx.x & 63, wid = threadIdx.x >> 6;
    if (lane == 0) { redE[wid] = eAcc; redP[wid] = pAcc; }
    __syncthreads();
    if (threadIdx.x == 0) {
        atomicAdd(ws + OFF_EXPS + b, redE[0] + redE[1] + redE[2] + redE[3]);
        atomicAdd(ws + OFF_POSS + b, redP[0] + redP[1] + redP[2] + redP[3]);
    }
}

// ---------------- Kernel 5: finalize scalar loss -----------------------------
__global__ void finalize_k(const float* __restrict__ ws, float* __restrict__ out)
{
    if (threadIdx.x == 0) {
        const float* expSum = ws + OFF_EXPS;
        const float* posSum = ws + OFF_POSS;
        float loss = 0.0f;
        for (int b = 0; b < kB; ++b)
            loss += -2.0f * posSum[b] / (float)kC + logf(expSum[b]);
        out[0] = loss / (float)kB;
    }
}

extern "C" void kernel_launch(void* const* d_in, const int* in_sizes, int n_in,
                              void* d_out, int out_size, void* d_ws, size_t ws_size,
                              hipStream_t stream)
{
    const float* ten = (const float*)d_in[0];   // teacher_vectors
    const float* stu = (const float*)d_in[1];   // student_vectors
    float* ws  = (float*)d_ws;
    float* out = (float*)d_out;

    // Pick the largest K-split whose psim fits in the workspace.
    int KS = 4;
    {
        size_t base = OFF_PSIM * 4ull;
        if (ws_size < base + 4ull * 16 * 65536 * 4) KS = 2;
        if (ws_size < base + 2ull * 16 * 65536 * 4) KS = 1;
    }
    int kIters = (kHW / KS) / 64;

    colnorm_k<<<dim3(256, 2), 256, 0, stream>>>(ten, stu, ws);
    rownorm_k<<<dim3(4096, 2), 256, 0, stream>>>(ten, stu, ws);
    gemm_part_k<<<dim3(256 * KS), 256, 0, stream>>>(ws, kIters);
    reduce_k<<<dim3(1024), 256, 0, stream>>>(ws, KS);
    finalize_k<<<1, 64, 0, stream>>>(ws, out);
}

// Round 3
// 94.147 us; speedup vs baseline: 1.2127x; 1.1731x over previous
//
#include <hip/hip_runtime.h>
#include <hip/hip_bf16.h>

typedef short bf16x8 __attribute__((ext_vector_type(8)));
typedef float f32x4 __attribute__((ext_vector_type(4)));

#define GLOAD(gp, lp)                                                          \
    __builtin_amdgcn_global_load_lds(                                          \
        (const __attribute__((address_space(1))) void*)(gp),                   \
        (__attribute__((address_space(3))) void*)(lp), 16, 0, 0)

// Problem sizes: B=16, C=256, HW=4096 (64*64)
static constexpr int kB = 16;
static constexpr int kC = 256;
static constexpr int kHW = 4096;

// Workspace layout (float offsets)
static constexpr int OFF_INVC_T = 0;        // 65536 floats
static constexpr int OFF_INVC_S = 65536;    // 65536 floats
static constexpr int OFF_INVD_T = 131072;   // 4096 floats
static constexpr int OFF_INVD_S = 135168;   // 4096 floats
static constexpr int OFF_EXPS   = 139264;   // 16 floats
static constexpr int OFF_POSS   = 139280;   // 16 floats
static constexpr size_t OFF_U_BYTES = 139296ull * 4ull;       // bf16 u_t then u_s
static constexpr size_t U_ELEMS = (size_t)kB * kC * kHW;      // 16777216 per tensor
// psim area after u. Also aliased (earlier in the stream) by colnorm partials:
// colnorm_part writes [16][65536] floats here, invc_fin consumes them, and only
// afterwards does gemm_part overwrite the region with its partial tiles.
static constexpr size_t OFF_PSIM = 139296ull + 16777216ull;   // float offset

// ---------------- Kernel 1a: channel-norm partials ---------------------------
// grid.x = 1024: [tensor(2)][b(16)][cslice(8)][hwchunk(4)]. Each thread owns
// 4 hw positions (float4) and reduces 32 channels -> 1 partial float4.
__global__ __launch_bounds__(256) void colnorm_part_k(const float* __restrict__ ten,
                                                      const float* __restrict__ stu,
                                                      float* __restrict__ ws)
{
    int tid = threadIdx.x;
    int t   = blockIdx.x;
    if (t == 0 && tid < 32) ws[OFF_EXPS + tid] = 0.0f;  // zero accumulators

    int hwc = t & 3;
    int cs  = (t >> 2) & 7;
    int b   = (t >> 5) & 15;
    int ts  = t >> 9;                    // 0 = teacher, 1 = student
    const float* src = ts ? stu : ten;

    int hw0 = hwc * 1024 + tid * 4;
    const float* p = src + (size_t)b * (kC * kHW) + (size_t)cs * 32 * kHW + hw0;

    float4 acc = {0.0f, 0.0f, 0.0f, 0.0f};
#pragma unroll 8
    for (int c = 0; c < 32; ++c) {
        float4 v = *(const float4*)(p + (size_t)c * kHW);
        acc.x += v.x * v.x;
        acc.y += v.y * v.y;
        acc.z += v.z * v.z;
        acc.w += v.w * v.w;
    }
    // partial[slice = ts*8+cs][b*4096 + hw0]
    float* part = ws + OFF_PSIM + ((size_t)(ts * 8 + cs) << 16) + b * kHW + hw0;
    *(float4*)part = acc;
}

// ---------------- Kernel 1b: finalize invC -----------------------------------
// 131072 outputs (tensor-major), each = rsqrt of 8 partial slices.
__global__ __launch_bounds__(256) void invc_fin_k(float* __restrict__ ws)
{
    int g0  = (blockIdx.x * 256 + threadIdx.x) * 4;   // 0..131071
    int ts  = g0 >> 16;
    int pos = g0 & 65535;

    const float* part = ws + OFF_PSIM + ((size_t)(ts * 8) << 16) + pos;
    float4 s = {0.0f, 0.0f, 0.0f, 0.0f};
#pragma unroll
    for (int cs = 0; cs < 8; ++cs) {
        float4 v = *(const float4*)(part + ((size_t)cs << 16));
        s.x += v.x; s.y += v.y; s.z += v.z; s.w += v.w;
    }
    float4 o;
    o.x = 1.0f / fmaxf(sqrtf(s.x), 1e-12f);
    o.y = 1.0f / fmaxf(sqrtf(s.y), 1e-12f);
    o.z = 1.0f / fmaxf(sqrtf(s.z), 1e-12f);
    o.w = 1.0f / fmaxf(sqrtf(s.w), 1e-12f);
    *(float4*)(ws + (ts ? OFF_INVC_S : OFF_INVC_T) + pos) = o;
}

// ---------------- Kernel 2: u = x*invC -> bf16, row norms over HW -----------
__device__ __forceinline__ unsigned short f2bf(float f) {
    __hip_bfloat16 h = __float2bfloat16(f);
    return __builtin_bit_cast(unsigned short, h);
}

__global__ void rownorm_k(const float* __restrict__ ten,
                          const float* __restrict__ stu,
                          float* __restrict__ ws)
{
    int tid = threadIdx.x;
    int bc  = blockIdx.x;               // b*256 + c
    int b   = bc >> 8;
    bool isT = (blockIdx.y == 0);
    const float* src  = isT ? ten : stu;
    const float* invC = ws + (isT ? OFF_INVC_T : OFF_INVC_S);
    float* invD       = ws + (isT ? OFF_INVD_T : OFF_INVD_S);
    unsigned short* u = (unsigned short*)((char*)ws + OFF_U_BYTES) + (isT ? 0 : U_ELEMS);

    size_t rowBase = (size_t)bc * kHW;
    const float* crow = invC + b * kHW;

    float ss = 0.0f;
#pragma unroll
    for (int it = 0; it < 4; ++it) {
        int off = it * 1024 + tid * 4;
        float4 v = *(const float4*)(src + rowBase + off);
        float4 s = *(const float4*)(crow + off);
        float u0 = v.x * s.x, u1 = v.y * s.y, u2 = v.z * s.z, u3 = v.w * s.w;
        ss += u0 * u0 + u1 * u1 + u2 * u2 + u3 * u3;
        ushort4 o;
        o.x = f2bf(u0); o.y = f2bf(u1); o.z = f2bf(u2); o.w = f2bf(u3);
        *(ushort4*)(u + rowBase + off) = o;
    }
#pragma unroll
    for (int o = 32; o; o >>= 1) ss += __shfl_down(ss, o);
    __shared__ float red[4];
    if ((tid & 63) == 0) red[tid >> 6] = ss;
    __syncthreads();
    if (tid == 0)
        invD[bc] = 1.0f / fmaxf(sqrtf(red[0] + red[1] + red[2] + red[3]), 1e-12f);
}

// ---------------- Kernel 3: batched GEMM partials (K-split) ------------------
__global__ __launch_bounds__(256) void gemm_part_k(float* __restrict__ ws,
                                                   int kIters)
{
    const unsigned short* uT = (const unsigned short*)((const char*)ws + OFF_U_BYTES);
    const unsigned short* uS = uT + U_ELEMS;
    float* psim = ws + OFF_PSIM;

    __shared__ __align__(16) unsigned short As[2][4096];
    __shared__ __align__(16) unsigned short Bs[2][4096];

    int tid = threadIdx.x;
    int bid = blockIdx.x;
    int cpx = gridDim.x >> 3;
    int w   = (bid & 7) * cpx + (bid >> 3);
    int tile = w & 15;
    int g    = w >> 4;
    int b    = g & 15;
    int kz   = g >> 4;
    int tr   = tile >> 2, tc = tile & 3;
    int lane = tid & 63, wid = tid >> 6;
    int wr   = wid >> 1, wc = wid & 1;

    int k0base = kz * (kIters * 64);

    int D0  = tid * 16;
    int r0s = D0 >> 7;
    int c0s = ((D0 & 127) ^ ((r0s & 7) << 4)) >> 1;
    int D1  = 4096 + tid * 16;
    int r1s = D1 >> 7;
    int c1s = ((D1 & 127) ^ ((r1s & 7) << 4)) >> 1;

    const unsigned short* gA = uS + ((size_t)(b * kC + tr * 64) << 12) + k0base;
    const unsigned short* gB = uT + ((size_t)(b * kC + tc * 64) << 12) + k0base;

    f32x4 acc[2][2] = {};

    GLOAD(gA + ((size_t)r0s << 12) + c0s, (char*)As[0] + D0);
    GLOAD(gA + ((size_t)r1s << 12) + c1s, (char*)As[0] + D1);
    GLOAD(gB + ((size_t)r0s << 12) + c0s, (char*)Bs[0] + D0);
    GLOAD(gB + ((size_t)r1s << 12) + c1s, (char*)Bs[0] + D1);
    __syncthreads();

    int cur = 0;
    for (int it = 0; it < kIters; ++it) {
        if (it + 1 < kIters) {
            int k0 = (it + 1) * 64;
            GLOAD(gA + ((size_t)r0s << 12) + k0 + c0s, (char*)As[cur ^ 1] + D0);
            GLOAD(gA + ((size_t)r1s << 12) + k0 + c1s, (char*)As[cur ^ 1] + D1);
            GLOAD(gB + ((size_t)r0s << 12) + k0 + c0s, (char*)Bs[cur ^ 1] + D0);
            GLOAD(gB + ((size_t)r1s << 12) + k0 + c1s, (char*)Bs[cur ^ 1] + D1);
        }
        const char* Ab = (const char*)As[cur];
        const char* Bb = (const char*)Bs[cur];
#pragma unroll
        for (int ks = 0; ks < 2; ++ks) {
            bf16x8 av[2], bv[2];
            int kb = ks * 64 + (lane >> 4) * 16;
#pragma unroll
            for (int f = 0; f < 2; ++f) {
                int row = wr * 32 + f * 16 + (lane & 15);
                av[f] = *(const bf16x8*)(Ab + (row << 7) + (kb ^ ((row & 7) << 4)));
                int col = wc * 32 + f * 16 + (lane & 15);
                bv[f] = *(const bf16x8*)(Bb + (col << 7) + (kb ^ ((col & 7) << 4)));
            }
#pragma unroll
            for (int fr = 0; fr < 2; ++fr)
#pragma unroll
                for (int fc = 0; fc < 2; ++fc)
                    acc[fr][fc] = __builtin_amdgcn_mfma_f32_16x16x32_bf16(
                        av[fr], bv[fc], acc[fr][fc], 0, 0, 0);
        }
        __syncthreads();
        cur ^= 1;
    }

    float* pt = psim + ((size_t)(kz * 16 + b) << 16);
#pragma unroll
    for (int fr = 0; fr < 2; ++fr)
#pragma unroll
        for (int fc = 0; fc < 2; ++fc) {
            int col = tc * 64 + wc * 32 + fc * 16 + (lane & 15);
#pragma unroll
            for (int j = 0; j < 4; ++j) {
                int row = tr * 64 + wr * 32 + fr * 16 + (lane >> 4) * 4 + j;
                pt[row * 256 + col] = acc[fr][fc][j];
            }
        }
}

// ---------------- Kernel 4: sum partials + scale + fused exp/diag reduce ----
__global__ __launch_bounds__(256) void reduce_k(float* __restrict__ ws, int KS)
{
    const float* psim  = ws + OFF_PSIM;
    const float* invDt = ws + OFF_INVD_T;
    const float* invDs = ws + OFF_INVD_S;

    int b     = blockIdx.x >> 6;
    int local = ((blockIdx.x & 63) << 10) + threadIdx.x * 4;   // 0..65535
    int row   = local >> 8;
    int col   = local & 255;

    float4 s = {0.0f, 0.0f, 0.0f, 0.0f};
    for (int ks = 0; ks < KS; ++ks) {
        float4 v = *(const float4*)(psim + (((size_t)(ks * 16 + b)) << 16) + local);
        s.x += v.x; s.y += v.y; s.z += v.z; s.w += v.w;
    }
    float  ds = invDs[b * 256 + row];
    float4 dt = *(const float4*)(invDt + b * 256 + col);
    float v0 = s.x * ds * dt.x;
    float v1 = s.y * ds * dt.y;
    float v2 = s.z * ds * dt.z;
    float v3 = s.w * ds * dt.w;

    float eAcc = __expf(2.0f * v0) + __expf(2.0f * v1) +
                 __expf(2.0f * v2) + __expf(2.0f * v3);
    float pAcc = 0.0f;
    if (row == col)     pAcc = v0;
    if (row == col + 1) pAcc = v1;
    if (row == col + 2) pAcc = v2;
    if (row == col + 3) pAcc = v3;

#pragma unroll
    for (int o = 32; o; o >>= 1) {
        eAcc += __shfl_down(eAcc, o);
        pAcc += __shfl_down(pAcc, o);
    }
    __shared__ float redE[4], redP[4];
    int lane = threadIdx.x & 63, wid = threadIdx.x >> 6;
    if (lane == 0) { redE[wid] = eAcc; redP[wid] = pAcc; }
    __syncthreads();
    if (threadIdx.x == 0) {
        atomicAdd(ws + OFF_EXPS + b, redE[0] + redE[1] + redE[2] + redE[3]);
        atomicAdd(ws + OFF_POSS + b, redP[0] + redP[1] + redP[2] + redP[3]);
    }
}

// ---------------- Kernel 5: finalize scalar loss -----------------------------
__global__ void finalize_k(const float* __restrict__ ws, float* __restrict__ out)
{
    if (threadIdx.x == 0) {
        const float* expSum = ws + OFF_EXPS;
        const float* posSum = ws + OFF_POSS;
        float loss = 0.0f;
        for (int b = 0; b < kB; ++b)
            loss += -2.0f * posSum[b] / (float)kC + logf(expSum[b]);
        out[0] = loss / (float)kB;
    }
}

extern "C" void kernel_launch(void* const* d_in, const int* in_sizes, int n_in,
                              void* d_out, int out_size, void* d_ws, size_t ws_size,
                              hipStream_t stream)
{
    const float* ten = (const float*)d_in[0];   // teacher_vectors
    const float* stu = (const float*)d_in[1];   // student_vectors
    float* ws  = (float*)d_ws;
    float* out = (float*)d_out;

    // Largest K-split whose psim fits the workspace (psim also needs >= 4 MB
    // for the colnorm partials; KS>=1 gives 16*65536*4B = 4 MB, exactly enough).
    int KS = 4;
    {
        size_t base = OFF_PSIM * 4ull;
        if (ws_size < base + 4ull * 16 * 65536 * 4) KS = 2;
        if (ws_size < base + 2ull * 16 * 65536 * 4) KS = 1;
    }
    int kIters = (kHW / KS) / 64;

    colnorm_part_k<<<dim3(1024), 256, 0, stream>>>(ten, stu, ws);
    invc_fin_k<<<dim3(128), 256, 0, stream>>>(ws);
    rownorm_k<<<dim3(4096, 2), 256, 0, stream>>>(ten, stu, ws);
    gemm_part_k<<<dim3(256 * KS), 256, 0, stream>>>(ws, kIters);
    reduce_k<<<dim3(1024), 256, 0, stream>>>(ws, KS);
    finalize_k<<<1, 64, 0, stream>>>(ws, out);
}